// Round 1
// baseline (98.793 us; speedup 1.0000x reference)
//
#include <hip/hip_runtime.h>

// Problem constants (hardcoded from reference):
//   x: (B=8, C=64, H=56, W=56) fp32, k=7, stride=1, pad=3, dilation=1, reflect pad
//   out: (B, C, 49, 56*56) fp32; out[b,c,ij,hw] = x[b,c,h,w] - x[b,c,refl(h+i-3),refl(w+j-3)]
#define HH 56
#define WW 56
#define KKS 7
#define PD 3
#define HWOUT (HH * WW)        // 3136
#define PLANES (8 * 64 * 49)   // 25088 output planes of HWOUT floats each

// Single-bounce reflection (np.pad mode='reflect'): valid for t in [-PD, HH-1+PD]
__device__ __forceinline__ int refl(int t) {
    t = (t < 0) ? -t : t;
    return (t >= HH) ? (2 * HH - 2 - t) : t;
}

__global__ __launch_bounds__(256) void sub_kernel(const float* __restrict__ x,
                                                  float* __restrict__ out) {
    const int plane = blockIdx.x;       // = bc*49 + ij
    const int ij = plane % 49;
    const int bc = plane / 49;
    const int di = (ij / KKS) - PD;     // row offset  in [-3, 3]
    const int dj = (ij % KKS) - PD;     // col offset  in [-3, 3]

    const float* __restrict__ img = x + (size_t)bc * HWOUT;  // one 56x56 image (12.5 KB, L1-resident)
    float* __restrict__ o = out + (size_t)plane * HWOUT;

    // 784 float4s per plane; 256 threads -> 4 strided iterations (last partial)
    for (int q = threadIdx.x; q < HWOUT / 4; q += 256) {
        const int e = q * 4;            // element offset in plane; 16B-aligned
        const int h = e / WW;
        const int w = e - h * WW;       // multiple of 4; all 4 lanes share row h

        const float4 cen = *reinterpret_cast<const float4*>(img + e);
        const float* __restrict__ row = img + refl(h + di) * WW;

        float4 r;
        r.x = cen.x - row[refl(w + 0 + dj)];
        r.y = cen.y - row[refl(w + 1 + dj)];
        r.z = cen.z - row[refl(w + 2 + dj)];
        r.w = cen.w - row[refl(w + 3 + dj)];

        *reinterpret_cast<float4*>(o + e) = r;
    }
}

extern "C" void kernel_launch(void* const* d_in, const int* in_sizes, int n_in,
                              void* d_out, int out_size, void* d_ws, size_t ws_size,
                              hipStream_t stream) {
    const float* x = (const float*)d_in[0];
    float* out = (float*)d_out;
    sub_kernel<<<dim3(PLANES), dim3(256), 0, stream>>>(x, out);
}

// Round 2
// 58.727 us; speedup vs baseline: 1.6822x; 1.6822x over previous
//
#include <hip/hip_runtime.h>

// x: (B=8, C=64, H=56, W=56) fp32; out: (B,C,49,3136) fp32
// out[b,c,(i*7+j),h*56+w] = x[b,c,h,w] - x[b,c, refl(h+i-3), refl(w+j-3)]
#define HH 56
#define WW 56
#define HWOUT (HH * WW)          // 3136
#define NBC (8 * 64)             // 512 images
#define NBLK (NBC * 7)           // block = (bc, di)

// Single-bounce reflection, valid for t in [-3, 58]
__device__ __forceinline__ int refl(int t) {
    t = (t < 0) ? -t : t;
    return (t >= HH) ? (2 * HH - 2 - t) : t;
}

__global__ __launch_bounds__(256) void sub_kernel(const float* __restrict__ x,
                                                  float* __restrict__ out) {
    const int blk = blockIdx.x;
    const int di = blk % 7;                  // row-offset index 0..6 (offset di-3)
    const int bc = blk / 7;

    const float* __restrict__ img = x + (size_t)bc * HWOUT;
    float* __restrict__ oplane0 = out + ((size_t)bc * 49 + (size_t)di * 7) * HWOUT;

    for (int q = threadIdx.x; q < HWOUT / 4; q += 256) {
        const int e = q * 4;                 // 16B-aligned element offset
        const int h = e / WW;
        const int w = e - h * WW;            // 0,4,...,52

        const float* __restrict__ crow = img + h * WW;
        const float* __restrict__ nrow = img + refl(h + di - 3) * WW;

        const float4 cen = *reinterpret_cast<const float4*>(crow + w);

        // wnd[idx] corresponds to nrow[w - 4 + idx]; idx 1..10 used.
        float wnd[12];
        {   // lo: nrow[w-4 .. w-1]; for w==0 load a safe dummy (patched below)
            const float4 lo = *reinterpret_cast<const float4*>(nrow + (w == 0 ? 0 : w - 4));
            wnd[0] = lo.x; wnd[1] = lo.y; wnd[2] = lo.z; wnd[3] = lo.w;
        }
        {   // mid: nrow[w .. w+3]
            const float4 mid = *reinterpret_cast<const float4*>(nrow + w);
            wnd[4] = mid.x; wnd[5] = mid.y; wnd[6] = mid.z; wnd[7] = mid.w;
        }
        {   // hi: nrow[w+4 .. w+7]; for w==52 load a safe dummy (patched below)
            const float4 hi = *reinterpret_cast<const float4*>(nrow + (w == 52 ? 48 : w + 4));
            wnd[8] = hi.x; wnd[9] = hi.y; wnd[10] = hi.z; wnd[11] = hi.w;
        }
        if (w == 0) {       // nrow[-3,-2,-1] -> nrow[3,2,1]
            wnd[1] = nrow[3]; wnd[2] = nrow[2]; wnd[3] = nrow[1];
        }
        if (w == 52) {      // nrow[56,57,58] -> nrow[54,53,52]
            wnd[8] = nrow[54]; wnd[9] = nrow[53]; wnd[10] = nrow[52];
        }

        float* __restrict__ op = oplane0 + e;
        #pragma unroll
        for (int djj = 0; djj < 7; ++djj) {  // dj = djj - 3; all wnd indices static
            float4 r;
            r.x = cen.x - wnd[djj + 1];
            r.y = cen.y - wnd[djj + 2];
            r.z = cen.z - wnd[djj + 3];
            r.w = cen.w - wnd[djj + 4];
            *reinterpret_cast<float4*>(op + (size_t)djj * HWOUT) = r;
        }
    }
}

extern "C" void kernel_launch(void* const* d_in, const int* in_sizes, int n_in,
                              void* d_out, int out_size, void* d_ws, size_t ws_size,
                              hipStream_t stream) {
    const float* x = (const float*)d_in[0];
    float* out = (float*)d_out;
    sub_kernel<<<dim3(NBLK), dim3(256), 0, stream>>>(x, out);
}